// Round 1
// baseline (111.453 us; speedup 1.0000x reference)
//
#include <hip/hip_runtime.h>
#include <hip/hip_bf16.h>
#include <stdint.h>

#define B_ 2
#define C_ 128
#define N_ 9216
#define MTILE 128
#define KTILE 64
#define NKT 144     // key tiles of 64
#define MT_N 72     // m tiles per batch

typedef __attribute__((ext_vector_type(4)))  float        f32x4;
typedef __attribute__((ext_vector_type(16))) float        f32x16;
typedef __attribute__((ext_vector_type(4)))  unsigned int u32x4;
typedef __bf16 bf16x8 __attribute__((ext_vector_type(8)));

typedef __attribute__((address_space(1))) unsigned int as1_uint;
typedef __attribute__((address_space(3))) unsigned int as3_uint;

__device__ __forceinline__ unsigned pkbf(float lo, float hi) {
  unsigned r;
  asm("v_cvt_pk_bf16_f32 %0, %1, %2" : "=v"(r) : "v"(lo), "v"(hi));
  return r;
}
__device__ __forceinline__ bf16x8 as_bf(u32x4 v) { return __builtin_bit_cast(bf16x8, v); }

__device__ __forceinline__ void gload16(const void* g, void* l) {
  __builtin_amdgcn_global_load_lds((const as1_uint*)g, (as3_uint*)l, 16, 0, 0);
}

// ---------------- prep: cast x (f32 [b][c][n]) -> bf16 same layout ----------------
__global__ __launch_bounds__(256) void cast_kernel(const float* __restrict__ x,
                                                   char* __restrict__ xb) {
  size_t i = ((size_t)blockIdx.x * 256 + threadIdx.x) * 8;
  f32x4 a = *(const f32x4*)(x + i);
  f32x4 b = *(const f32x4*)(x + i + 4);
  u32x4 r = { pkbf(a[0], a[1]), pkbf(a[2], a[3]), pkbf(b[0], b[1]), pkbf(b[2], b[3]) };
  *(u32x4*)(xb + i * 2) = r;
}

// ---------------- prep: Q/K projections -> bf16 [b][n][16] rows of 32B ----------------
__global__ __launch_bounds__(256) void qk_kernel(const float* __restrict__ y,
                                                 const float* __restrict__ wq,
                                                 const float* __restrict__ wk,
                                                 char* __restrict__ Qp,
                                                 char* __restrict__ Kp) {
  __shared__ float wt[2][128][16];   // [sel][c][o] transposed weights
  __shared__ float red[256][32];
  const int tid = threadIdx.x;
#pragma unroll
  for (int i2 = 0; i2 < 16; ++i2) {
    int g = tid + 256 * i2;          // 0..4095
    int sel = g >> 11;
    int rem = g & 2047;
    int c = rem & 127;
    int o = rem >> 7;
    wt[sel][c][o] = sel ? wk[o * 128 + c] : wq[o * 128 + c];
  }
  __syncthreads();
  const int nl = tid & 63, cg = tid >> 6;
  const int gn = blockIdx.x * 64 + nl;
  const int bi = gn / N_, n = gn % N_;
  float aq[16], ak[16];
#pragma unroll
  for (int o = 0; o < 16; ++o) { aq[o] = 0.f; ak[o] = 0.f; }
  const float* yb = y + (size_t)bi * C_ * N_ + n;
  for (int ci = 0; ci < 32; ++ci) {
    int c = cg * 32 + ci;
    float yv = yb[(size_t)c * N_];
    f32x4 q0 = *(const f32x4*)&wt[0][c][0];
    f32x4 q1 = *(const f32x4*)&wt[0][c][4];
    f32x4 q2 = *(const f32x4*)&wt[0][c][8];
    f32x4 q3 = *(const f32x4*)&wt[0][c][12];
    f32x4 k0 = *(const f32x4*)&wt[1][c][0];
    f32x4 k1 = *(const f32x4*)&wt[1][c][4];
    f32x4 k2 = *(const f32x4*)&wt[1][c][8];
    f32x4 k3 = *(const f32x4*)&wt[1][c][12];
#pragma unroll
    for (int j = 0; j < 4; ++j) {
      aq[j]      = fmaf(q0[j], yv, aq[j]);
      aq[4 + j]  = fmaf(q1[j], yv, aq[4 + j]);
      aq[8 + j]  = fmaf(q2[j], yv, aq[8 + j]);
      aq[12 + j] = fmaf(q3[j], yv, aq[12 + j]);
      ak[j]      = fmaf(k0[j], yv, ak[j]);
      ak[4 + j]  = fmaf(k1[j], yv, ak[4 + j]);
      ak[8 + j]  = fmaf(k2[j], yv, ak[8 + j]);
      ak[12 + j] = fmaf(k3[j], yv, ak[12 + j]);
    }
  }
#pragma unroll
  for (int o = 0; o < 16; ++o) { red[tid][o] = aq[o]; red[tid][16 + o] = ak[o]; }
  __syncthreads();
  const int nl2 = tid & 63, og = tid >> 6;
  const int gn2 = blockIdx.x * 64 + nl2;
  float v[8];
#pragma unroll
  for (int j = 0; j < 8; ++j) {
    int o = og * 8 + j;
    v[j] = red[nl2][o] + red[64 + nl2][o] + red[128 + nl2][o] + red[192 + nl2][o];
  }
  u32x4 r = { pkbf(v[0], v[1]), pkbf(v[2], v[3]), pkbf(v[4], v[5]), pkbf(v[6], v[7]) };
  char* dst = (og < 2) ? Qp : Kp;
  *(u32x4*)(dst + (size_t)gn2 * 32 + (og & 1) * 16) = r;
}

// ---------------- attention: O^T[c][m] partials + sum-exp partials ----------------
__global__ __launch_bounds__(256, 2) void attn_kernel(const char* __restrict__ xb,
                                                      const char* __restrict__ Qp,
                                                      const char* __restrict__ Kp,
                                                      float* __restrict__ Opart,
                                                      float* __restrict__ Epart,
                                                      int S) {
  __shared__ __align__(128) char smem[32768];   // 2 x 16KB x-tile buffers
  const int tid = threadIdx.x;
  const int l = tid & 63, wv = tid >> 6;
  const int h = l >> 5, ml = l & 31;

  // XCD-aware decode: XCDs 0-3 -> batch 0, XCDs 4-7 -> batch 1
  const int bid = blockIdx.x;
  const int xcd = bid & 7;
  const int bi = xcd >> 2;
  const int slot = (bid >> 3) * 4 + (xcd & 3);  // 0 .. 72*S-1
  const int mt = slot / S;
  const int s = slot - mt * S;
  const int ktper = NKT / S;
  const int kt0 = s * ktper, ktE = kt0 + ktper;
  const int mw = mt * MTILE + wv * 32;

  // Q fragment (B-operand): lane: m = ml, k = 8h+j
  bf16x8 qf = as_bf(*(const u32x4*)(Qp + (size_t)(bi * N_ + mw + ml) * 32 + h * 16));

  f32x16 acc0 = {}, acc1 = {}, acc2 = {}, acc3 = {};
  float se = 0.f;

  const size_t xrow = (size_t)N_ * 2;
  const char* gbase = xb + (size_t)bi * C_ * N_ * 2;

  auto stage = [&](int buf, int kt) {
    const char* gb = gbase + (size_t)kt * KTILE * 2;
#pragma unroll
    for (int j = 0; j < 4; ++j) {
      int reg = wv * 4 + j;                 // 16 regions of 8 c-rows
      int c = reg * 8 + (l >> 3);
      int t = (l & 7) ^ ((l >> 3) & 7);     // pre-swizzled source chunk
      const char* ga = gb + (size_t)c * xrow + t * 16;
      char* lb = smem + buf * 16384 + reg * 1024;   // wave-uniform dest
      gload16(ga, lb);
    }
  };

  stage(0, kt0);
  __syncthreads();
  int cur = 0;
  for (int kt = kt0; kt < ktE; ++kt) {
    if (kt + 1 < ktE) stage(cur ^ 1, kt + 1);

    // S^T = mfma(K, Q): D[key][m]
    const char* kb = Kp + (size_t)(bi * N_ + kt * KTILE) * 32;
    bf16x8 kf0 = as_bf(*(const u32x4*)(kb + ml * 32 + h * 16));
    bf16x8 kf1 = as_bf(*(const u32x4*)(kb + 1024 + ml * 32 + h * 16));
    f32x16 z = {};
    f32x16 s0 = __builtin_amdgcn_mfma_f32_32x32x16_bf16(kf0, qf, z, 0, 0, 0);
    f32x16 s1 = __builtin_amdgcn_mfma_f32_32x32x16_bf16(kf1, qf, z, 0, 0, 0);

    float p[32];
#pragma unroll
    for (int r = 0; r < 16; ++r) { p[r] = __expf(s0[r]); p[16 + r] = __expf(s1[r]); }
#pragma unroll
    for (int r = 0; r < 32; ++r) se += p[r];

    // build PV B-fragments in-register (cvt_pk + half-wave exchange)
    u32x4 bw[4];
    const bool lo = (l < 32);
#pragma unroll
    for (int t = 0; t < 4; ++t) {
      int base = (t >> 1) * 16 + (t & 1) * 8;
      unsigned a  = pkbf(p[base + 0], p[base + 1]);
      unsigned b  = pkbf(p[base + 4], p[base + 5]);
      unsigned c2 = pkbf(p[base + 2], p[base + 3]);
      unsigned d  = pkbf(p[base + 6], p[base + 7]);
      unsigned as2 = (unsigned)__shfl_xor((int)a, 32, 64);
      unsigned bs2 = (unsigned)__shfl_xor((int)b, 32, 64);
      unsigned cs2 = (unsigned)__shfl_xor((int)c2, 32, 64);
      unsigned ds2 = (unsigned)__shfl_xor((int)d, 32, 64);
      bw[t] = (u32x4){ lo ? a : bs2, lo ? c2 : ds2, lo ? as2 : b, lo ? cs2 : d };
    }

    // PV: acc[cs] += x_frag * P_frag   (A from swizzled LDS x-tile)
    const char* lbase = smem + cur * 16384;
#pragma unroll
    for (int t = 0; t < 4; ++t) {
      bf16x8 pb = as_bf(bw[t]);
#pragma unroll
      for (int cs = 0; cs < 4; ++cs) {
        const u32x4* ap =
            (const u32x4*)(lbase + cs * 4096 + ml * 128 + (((2 * t + h) ^ (ml & 7)) * 16));
        bf16x8 af = as_bf(*ap);
        if      (cs == 0) acc0 = __builtin_amdgcn_mfma_f32_32x32x16_bf16(af, pb, acc0, 0, 0, 0);
        else if (cs == 1) acc1 = __builtin_amdgcn_mfma_f32_32x32x16_bf16(af, pb, acc1, 0, 0, 0);
        else if (cs == 2) acc2 = __builtin_amdgcn_mfma_f32_32x32x16_bf16(af, pb, acc2, 0, 0, 0);
        else              acc3 = __builtin_amdgcn_mfma_f32_32x32x16_bf16(af, pb, acc3, 0, 0, 0);
      }
    }
    __syncthreads();
    cur ^= 1;
  }

  // epilogue
  float set = se + __shfl_xor(se, 32, 64);
  const int m = mw + ml;
  const size_t sb = (size_t)(s * B_ + bi);
  if (l < 32) Epart[sb * N_ + m] = set;
  float* ob = Opart + (sb * N_ + m) * (size_t)C_;
#pragma unroll
  for (int cs = 0; cs < 4; ++cs) {
    const f32x16& A = (cs == 0) ? acc0 : (cs == 1) ? acc1 : (cs == 2) ? acc2 : acc3;
#pragma unroll
    for (int g = 0; g < 4; ++g) {
      f32x4 v = { A[4 * g], A[4 * g + 1], A[4 * g + 2], A[4 * g + 3] };
      *(f32x4*)(ob + cs * 32 + g * 8 + h * 4) = v;
    }
  }
}

// ---------------- combine partials, normalize, apply w_v, write out ----------------
template <int NS>
__global__ __launch_bounds__(64) void combine_kernel(const float* __restrict__ Opart,
                                                     const float* __restrict__ Epart,
                                                     const float* __restrict__ wv,
                                                     float* __restrict__ out) {
  const int l = threadIdx.x;
  const int h = l >> 5, ml = l & 31;
  const int bid = blockIdx.x;
  const int bi = bid / 288;
  const int m0 = (bid % 288) * 32;
  const int m = m0 + ml;

  float e = 0.f;
#pragma unroll
  for (int s2 = 0; s2 < NS; ++s2) e += Epart[(size_t)(s2 * B_ + bi) * N_ + m];
  const float einv = 1.0f / e;

  f32x16 acc[4] = { {}, {}, {}, {} };
#pragma unroll
  for (int ks = 0; ks < 8; ++ks) {
    float o8[8];
#pragma unroll
    for (int j = 0; j < 8; ++j) o8[j] = 0.f;
#pragma unroll
    for (int s2 = 0; s2 < NS; ++s2) {
      const float* op =
          Opart + ((size_t)(s2 * B_ + bi) * N_ + m) * C_ + ks * 16 + h * 8;
      f32x4 v0 = *(const f32x4*)op;
      f32x4 v1 = *(const f32x4*)(op + 4);
#pragma unroll
      for (int j = 0; j < 4; ++j) { o8[j] += v0[j]; o8[4 + j] += v1[j]; }
    }
    u32x4 bwv = { pkbf(o8[0] * einv, o8[1] * einv), pkbf(o8[2] * einv, o8[3] * einv),
                  pkbf(o8[4] * einv, o8[5] * einv), pkbf(o8[6] * einv, o8[7] * einv) };
    bf16x8 bf = as_bf(bwv);
#pragma unroll
    for (int is = 0; is < 4; ++is) {
      const float* ap = wv + (size_t)(is * 32 + ml) * C_ + ks * 16 + h * 8;
      f32x4 a0 = *(const f32x4*)ap;
      f32x4 a1 = *(const f32x4*)(ap + 4);
      u32x4 aw = { pkbf(a0[0], a0[1]), pkbf(a0[2], a0[3]), pkbf(a1[0], a1[1]),
                   pkbf(a1[2], a1[3]) };
      acc[is] = __builtin_amdgcn_mfma_f32_32x32x16_bf16(as_bf(aw), bf, acc[is], 0, 0, 0);
    }
  }
  float* ob = out + (size_t)bi * C_ * N_ + m;
#pragma unroll
  for (int is = 0; is < 4; ++is) {
#pragma unroll
    for (int r = 0; r < 16; ++r) {
      int co = is * 32 + (r & 3) + 8 * (r >> 2) + 4 * h;
      ob[(size_t)co * N_] = acc[is][r];
    }
  }
}

extern "C" void kernel_launch(void* const* d_in, const int* in_sizes, int n_in,
                              void* d_out, int out_size, void* d_ws, size_t ws_size,
                              hipStream_t stream) {
  const float* x  = (const float*)d_in[0];
  const float* y  = (const float*)d_in[1];
  const float* wq = (const float*)d_in[2];
  const float* wk = (const float*)d_in[3];
  const float* wv = (const float*)d_in[4];
  float* out = (float*)d_out;
  char* ws = (char*)d_ws;

  const size_t XB = (size_t)B_ * C_ * N_ * 2;
  const size_t QKsz = (size_t)B_ * N_ * 16 * 2;
  int S = 4;
  auto need = [&](int s) {
    return XB + 2 * QKsz + (size_t)s * B_ * N_ * 4 + (size_t)s * B_ * N_ * C_ * 4;
  };
  while (S > 1 && need(S) > ws_size) S >>= 1;

  char* xb = ws;
  char* Qp = ws + XB;
  char* Kp = Qp + QKsz;
  float* Epart = (float*)(Kp + QKsz);
  float* Opart = (float*)((char*)Epart + (size_t)S * B_ * N_ * 4);

  cast_kernel<<<1152, 256, 0, stream>>>(x, xb);
  qk_kernel<<<288, 256, 0, stream>>>(y, wq, wk, Qp, Kp);
  attn_kernel<<<B_ * MT_N * S, 256, 0, stream>>>(xb, Qp, Kp, Opart, Epart, S);
  if (S == 4)      combine_kernel<4><<<B_ * 288, 64, 0, stream>>>(Opart, Epart, wv, out);
  else if (S == 2) combine_kernel<2><<<B_ * 288, 64, 0, stream>>>(Opart, Epart, wv, out);
  else             combine_kernel<1><<<B_ * 288, 64, 0, stream>>>(Opart, Epart, wv, out);
}